// Round 1
// baseline (315.154 us; speedup 1.0000x reference)
//
#include <hip/hip_runtime.h>

// SimpleEncoder R6: LSTM(B=4096,S=512,I=3,H=16) + Linear(16->5) + clip(+-10)
//
// R5 was issue-bound at 1 wave/SIMD (VALUBusy 60%, MfmaUtil 0, ~717 cyc/step):
// 48 MAC-instrs (W_hh.h, W_lin.h) + 16 DPP row-bcasts + act per step on the
// vector pipe. R6 moves ALL matvecs to the matrix pipe:
//   gates(64x4) = [W_hh|W_ih].[h;x] : 4 gates x 3-term bf16x2 MFMA (16x16x32)
//   out(5x4)    = W_lin.h           : 3-term MFMA on the same B-fragment
// bf16x2 compensated products (Whi*Bhi + Whi*Blo + Wlo*Bhi, truncation split)
// keep matvec error ~2^-16 relative; activations stay exact-f32.
//
// Layout: C/D of mfma_f32_16x16x32_bf16 is col=lane&15, row=(lane>>4)*4+reg
// (m89/m91-verified). A/B fragments contract POSITION-wise when both sides use
// the same (quad, element) -> k convention, so no dependence on the HW k-perm.
// Wave owns 4 batches (cols 0-3; cols 4-15 compute duplicates, masked at the
// scatter). Per step: B-frag <- hbuf (packed {hi,lo} bf16 per k; 2 ds_read_b128
// + 8 v_perm) -> 15 MFMA -> scatter z (4 masked b128 writes) -> gather 4 gate
// pre-acts/lane -> cell update with ALL 64 lanes valid (unit=lane&15,
// batch=quad) -> publish h_s, x_{s+1} pre-split to bf16. No DPP, no barriers
// (all LDS intra-wave, in-order per wave). LDS strides picked for <=2-way
// banking (zbuf stride 80 dw == 16 mod 32; hbuf stride 36 dw).
// Grid/occupancy unchanged: 256 blocks x 256 thr = 1024 waves = 1/SIMD.

#define TS 512
#define LOG2E 1.44269504088896340736f

typedef float f32x4 __attribute__((ext_vector_type(4)));
typedef short s16x8 __attribute__((ext_vector_type(8)));
typedef unsigned int u32;
typedef u32 u32x4 __attribute__((ext_vector_type(4)));
typedef f32x4 f32x4u __attribute__((aligned(4)));   // out rows are only 4B-aligned

static __device__ __forceinline__ float clip10(float v) {
  return fminf(fmaxf(v, -10.0f), 10.0f);
}

__global__ __launch_bounds__(256)
__attribute__((amdgpu_waves_per_eu(1, 1)))
void lstm_enc_kernel(const float* __restrict__ x,
                     const float* __restrict__ W_ih,
                     const float* __restrict__ W_hh,
                     const float* __restrict__ b_ih,
                     const float* __restrict__ b_hh,
                     const float* __restrict__ W_lin,
                     const float* __restrict__ b_lin,
                     float* __restrict__ out) {
  const int tid = threadIdx.x;
  const int w   = tid >> 6;         // wave in block (0..3)
  const int q   = (tid >> 4) & 3;   // quad within wave
  const int col = tid & 15;         // MFMA col / A row / act unit
  const int g16 = tid >> 4;         // block-level group (= w*4+q): staging slot

  __shared__ float4 xs[2][64][16];                                // x staging
  __shared__ f32x4  zbuf[4][4][20];                               // [wave][batch][G*4+q]
  __shared__ __attribute__((aligned(16))) u32 hbuf[4][4][36];     // [wave][batch][k] packed {hi,lo}

  float4* xsf = &xs[0][0][0];
  float*  zf  = (float*)&zbuf[w][0][0];
  u32*    hb  = &hbuf[w][0][0];

  // ---- A-fragments (once). Our convention: logical k = q*8 + e, same on A & B.
  // k<16: W_hh[gate row][k]; k=16..18: W_ih[gate row][k-16]; else 0. LOG2E folded
  // (2x for g-gate). Truncation split: v = hi + lo exactly at bf16x2 precision.
  s16x8 a_hi[4], a_lo[4];
#pragma unroll
  for (int G = 0; G < 4; ++G) {
    const float sc = (G == 2) ? (2.0f * LOG2E) : LOG2E;
#pragma unroll
    for (int e = 0; e < 8; ++e) {
      const int k = q * 8 + e;
      float v = 0.0f;
      if (k < 16)      v = W_hh[(G * 16 + col) * 16 + k] * sc;
      else if (k < 19) v = W_ih[(G * 16 + col) * 3 + (k - 16)] * sc;
      const u32 vb = __float_as_uint(v);
      const float hif = __uint_as_float(vb & 0xFFFF0000u);
      const float lof = v - hif;
      a_hi[G][e] = (short)(vb >> 16);
      a_lo[G][e] = (short)(__float_as_uint(lof) >> 16);
    }
  }
  s16x8 l_hi, l_lo;
#pragma unroll
  for (int e = 0; e < 8; ++e) {
    const int k = q * 8 + e;
    const float v = (col < 5 && k < 16) ? W_lin[col * 16 + k] : 0.0f;
    const u32 vb = __float_as_uint(v);
    const float hif = __uint_as_float(vb & 0xFFFF0000u);
    const float lof = v - hif;
    l_hi[e] = (short)(vb >> 16);
    l_lo[e] = (short)(__float_as_uint(lof) >> 16);
  }
  // C-init biases: D row = 4q + reg.
  f32x4 bias_c[4];
#pragma unroll
  for (int G = 0; G < 4; ++G) {
    const float sc = (G == 2) ? (2.0f * LOG2E) : LOG2E;
#pragma unroll
    for (int r = 0; r < 4; ++r)
      bias_c[G][r] = (b_ih[G * 16 + q * 4 + r] + b_hh[G * 16 + q * 4 + r]) * sc;
  }
  f32x4 blin_c;
#pragma unroll
  for (int r = 0; r < 4; ++r) {
    const int row = q * 4 + r;
    blin_c[r] = (row < 5) ? b_lin[row] : 0.0f;
  }

  // ---- x staging (identical scheme to R5: intra-wave, 64-step chunks, dbuf)
  const int batch_g = blockIdx.x * 16 + g16;
  const float* __restrict__ xb = x + (size_t)batch_g * (TS * 3);
  const float* xc0 = xb + col * 12;
  float4 p0, p1, p2;
  p0 = *(const float4*)(xc0 + 0);
  p1 = *(const float4*)(xc0 + 4);
  p2 = *(const float4*)(xc0 + 8);
  {
    const int wb = col * 64 + g16;
    xsf[wb +  0] = float4{p0.x, p0.y, p0.z, 0.f};
    xsf[wb + 16] = float4{p0.w, p1.x, p1.y, 0.f};
    xsf[wb + 32] = float4{p1.z, p1.w, p2.x, 0.f};
    xsf[wb + 48] = float4{p2.y, p2.z, p2.w, 0.f};
  }
  p0 = *(const float4*)(xc0 + 192 + 0);
  p1 = *(const float4*)(xc0 + 192 + 4);
  p2 = *(const float4*)(xc0 + 192 + 8);

  // ---- hbuf init: h_{-1}=0, pad k=19..31 zero; then publish x_0.
  {
    const int l = tid & 63;
#pragma unroll
    for (int i = 0; i < 3; ++i) {
      const int idx = l + i * 64;
      if (idx < 144) hb[idx] = 0;
    }
    const float4 xt0 = xsf[g16];  // step 0
    const float xv = (col == 0) ? xt0.x : ((col == 1) ? xt0.y : xt0.z);
    if (col < 3) {
      const u32 xbits = __float_as_uint(xv);
      const float xhi = __uint_as_float(xbits & 0xFFFF0000u);
      const float xlo = xv - xhi;
      hb[q * 36 + 16 + col] = __builtin_amdgcn_perm(xbits, __float_as_uint(xlo), 0x07060302u);
    }
  }

  float* __restrict__ ob = out + (size_t)(blockIdx.x * 16 + w * 4 + (col & 3)) * (TS * 5);
  float c = 0.0f;

  auto step = [&](int s) {
    // x for step s+1 (independent LDS read: issue early, consume late)
    const float4 xt = xsf[(((s + 1) & 127) << 4) + g16];

    // B-fragment from hbuf: packed dwords -> {hi,lo} bf16 frags (8 v_perm)
    const int hoff = (col & 3) * 36 + q * 8;
    const u32x4 d0 = *(const u32x4*)&hb[hoff];
    const u32x4 d1 = *(const u32x4*)&hb[hoff + 4];
    u32x4 hi4, lo4;
    hi4.x = __builtin_amdgcn_perm(d0.y, d0.x, 0x07060302u);
    lo4.x = __builtin_amdgcn_perm(d0.y, d0.x, 0x05040100u);
    hi4.y = __builtin_amdgcn_perm(d0.w, d0.z, 0x07060302u);
    lo4.y = __builtin_amdgcn_perm(d0.w, d0.z, 0x05040100u);
    hi4.z = __builtin_amdgcn_perm(d1.y, d1.x, 0x07060302u);
    lo4.z = __builtin_amdgcn_perm(d1.y, d1.x, 0x05040100u);
    hi4.w = __builtin_amdgcn_perm(d1.w, d1.z, 0x07060302u);
    lo4.w = __builtin_amdgcn_perm(d1.w, d1.z, 0x05040100u);
    const s16x8 Bhi = __builtin_bit_cast(s16x8, hi4);
    const s16x8 Blo = __builtin_bit_cast(s16x8, lo4);

    // gates: z_G = Whi*Bhi + Whi*Blo + Wlo*Bhi + bias (4 independent chains)
    f32x4 z0 = __builtin_amdgcn_mfma_f32_16x16x32_bf16(a_lo[0], Bhi, bias_c[0], 0, 0, 0);
    f32x4 z1 = __builtin_amdgcn_mfma_f32_16x16x32_bf16(a_lo[1], Bhi, bias_c[1], 0, 0, 0);
    f32x4 z2 = __builtin_amdgcn_mfma_f32_16x16x32_bf16(a_lo[2], Bhi, bias_c[2], 0, 0, 0);
    f32x4 z3 = __builtin_amdgcn_mfma_f32_16x16x32_bf16(a_lo[3], Bhi, bias_c[3], 0, 0, 0);
    f32x4 ov = __builtin_amdgcn_mfma_f32_16x16x32_bf16(l_lo,    Bhi, blin_c,    0, 0, 0);
    z0 = __builtin_amdgcn_mfma_f32_16x16x32_bf16(a_hi[0], Blo, z0, 0, 0, 0);
    z1 = __builtin_amdgcn_mfma_f32_16x16x32_bf16(a_hi[1], Blo, z1, 0, 0, 0);
    z2 = __builtin_amdgcn_mfma_f32_16x16x32_bf16(a_hi[2], Blo, z2, 0, 0, 0);
    z3 = __builtin_amdgcn_mfma_f32_16x16x32_bf16(a_hi[3], Blo, z3, 0, 0, 0);
    ov = __builtin_amdgcn_mfma_f32_16x16x32_bf16(l_hi,    Blo, ov, 0, 0, 0);
    z0 = __builtin_amdgcn_mfma_f32_16x16x32_bf16(a_hi[0], Bhi, z0, 0, 0, 0);
    z1 = __builtin_amdgcn_mfma_f32_16x16x32_bf16(a_hi[1], Bhi, z1, 0, 0, 0);
    z2 = __builtin_amdgcn_mfma_f32_16x16x32_bf16(a_hi[2], Bhi, z2, 0, 0, 0);
    z3 = __builtin_amdgcn_mfma_f32_16x16x32_bf16(a_hi[3], Bhi, z3, 0, 0, 0);
    ov = __builtin_amdgcn_mfma_f32_16x16x32_bf16(l_hi,    Bhi, ov, 0, 0, 0);

    // scatter gate pre-acts: C-layout (rows 4q..4q+3, col) -> zbuf[batch][G*16+row]
    if (col < 4) {
      zbuf[w][col][0 * 4 + q] = z0;
      zbuf[w][col][1 * 4 + q] = z1;
      zbuf[w][col][2 * 4 + q] = z2;
      zbuf[w][col][3 * 4 + q] = z3;
    }

    // linear head (h_{s-1} -> out[s-1]); rows: q0 -> outs 0-3, q1 reg0 -> out4
    if (s > 0 && col < 4) {
      if (q == 0) {
        f32x4 o;
        o.x = clip10(ov.x); o.y = clip10(ov.y); o.z = clip10(ov.z); o.w = clip10(ov.w);
        *(f32x4u*)(ob + (s - 1) * 5) = o;
      } else if (q == 1) {
        ob[(s - 1) * 5 + 4] = clip10(ov.x);
      }
    }

    // gather this lane's gate quartet: unit = col, batch = q (all lanes valid)
    const int zo_ = q * 80 + col;
    const float zi  = zf[zo_ +  0];
    const float zfg = zf[zo_ + 16];
    const float zg  = zf[zo_ + 32];
    const float zo  = zf[zo_ + 48];

    // activations (identical math to R5; log2e pre-folded)
    const float ig = __builtin_amdgcn_rcpf(1.0f + __builtin_amdgcn_exp2f(-zi));
    const float fg = __builtin_amdgcn_rcpf(1.0f + __builtin_amdgcn_exp2f(-zfg));
    const float sg = __builtin_amdgcn_rcpf(1.0f + __builtin_amdgcn_exp2f(zg));
    const float og = __builtin_amdgcn_rcpf(1.0f + __builtin_amdgcn_exp2f(-zo));
    const float gg = fmaf(-2.0f, sg, 1.0f);
    c = fmaf(fg, c, ig * gg);
    const float tc = fmaf(-2.0f,
        __builtin_amdgcn_rcpf(1.0f + __builtin_amdgcn_exp2f((2.0f * LOG2E) * c)), 1.0f);
    const float h = og * tc;

    // publish h_s (bf16 hi/lo packed in one dword) and x_{s+1}
    const u32 hbits = __float_as_uint(h);
    const float hhi = __uint_as_float(hbits & 0xFFFF0000u);
    const float hlo = h - hhi;
    hb[q * 36 + col] = __builtin_amdgcn_perm(hbits, __float_as_uint(hlo), 0x07060302u);

    const float xv = (col == 0) ? xt.x : ((col == 1) ? xt.y : xt.z);
    if (col < 3) {
      const u32 xbits = __float_as_uint(xv);
      const float xhi = __uint_as_float(xbits & 0xFFFF0000u);
      const float xlo = xv - xhi;
      hb[q * 36 + 16 + col] = __builtin_amdgcn_perm(xbits, __float_as_uint(xlo), 0x07060302u);
    }
  };

  for (int ch = 0; ch < 8; ++ch) {
    const int base = ch * 64;
#pragma unroll 2
    for (int u = 0; u < 32; ++u) step(base + u);

    // mid-chunk: stage chunk ch+1 (regs loaded ~64 steps ago), start ch+2 loads
    if (ch < 7) {
      const int p = (ch + 1) & 1;
      const int wb = p * 1024 + col * 64 + g16;
      xsf[wb +  0] = float4{p0.x, p0.y, p0.z, 0.f};
      xsf[wb + 16] = float4{p0.w, p1.x, p1.y, 0.f};
      xsf[wb + 32] = float4{p1.z, p1.w, p2.x, 0.f};
      xsf[wb + 48] = float4{p2.y, p2.z, p2.w, 0.f};
    }
    if (ch < 6) {
      const float* xc = xc0 + (ch + 2) * 192;
      p0 = *(const float4*)(xc + 0);
      p1 = *(const float4*)(xc + 4);
      p2 = *(const float4*)(xc + 8);
    }

#pragma unroll 2
    for (int u = 32; u < 64; ++u) step(base + u);
  }

  // epilogue: out[S-1] from h_{S-1} (x slots in B are ignored by l_* zeros)
  {
    const int hoff = (col & 3) * 36 + q * 8;
    const u32x4 d0 = *(const u32x4*)&hb[hoff];
    const u32x4 d1 = *(const u32x4*)&hb[hoff + 4];
    u32x4 hi4, lo4;
    hi4.x = __builtin_amdgcn_perm(d0.y, d0.x, 0x07060302u);
    lo4.x = __builtin_amdgcn_perm(d0.y, d0.x, 0x05040100u);
    hi4.y = __builtin_amdgcn_perm(d0.w, d0.z, 0x07060302u);
    lo4.y = __builtin_amdgcn_perm(d0.w, d0.z, 0x05040100u);
    hi4.z = __builtin_amdgcn_perm(d1.y, d1.x, 0x07060302u);
    lo4.z = __builtin_amdgcn_perm(d1.y, d1.x, 0x05040100u);
    hi4.w = __builtin_amdgcn_perm(d1.w, d1.z, 0x07060302u);
    lo4.w = __builtin_amdgcn_perm(d1.w, d1.z, 0x05040100u);
    const s16x8 Bhi = __builtin_bit_cast(s16x8, hi4);
    const s16x8 Blo = __builtin_bit_cast(s16x8, lo4);
    f32x4 ov = __builtin_amdgcn_mfma_f32_16x16x32_bf16(l_lo, Bhi, blin_c, 0, 0, 0);
    ov = __builtin_amdgcn_mfma_f32_16x16x32_bf16(l_hi, Blo, ov, 0, 0, 0);
    ov = __builtin_amdgcn_mfma_f32_16x16x32_bf16(l_hi, Bhi, ov, 0, 0, 0);
    if (col < 4) {
      if (q == 0) {
        f32x4 o;
        o.x = clip10(ov.x); o.y = clip10(ov.y); o.z = clip10(ov.z); o.w = clip10(ov.w);
        *(f32x4u*)(ob + (TS - 1) * 5) = o;
      } else if (q == 1) {
        ob[(TS - 1) * 5 + 4] = clip10(ov.x);
      }
    }
  }
}

extern "C" void kernel_launch(void* const* d_in, const int* in_sizes, int n_in,
                              void* d_out, int out_size, void* d_ws, size_t ws_size,
                              hipStream_t stream) {
  const float* x     = (const float*)d_in[0];
  const float* W_ih  = (const float*)d_in[1];
  const float* W_hh  = (const float*)d_in[2];
  const float* b_ih  = (const float*)d_in[3];
  const float* b_hh  = (const float*)d_in[4];
  const float* W_lin = (const float*)d_in[5];
  const float* b_lin = (const float*)d_in[6];
  float* out = (float*)d_out;

  const int B = in_sizes[0] / (TS * 3);   // 4096
  const int grid = B / 16;                // 16 batch elements per 256-thread block
  lstm_enc_kernel<<<grid, 256, 0, stream>>>(x, W_ih, W_hh, b_ih, b_hh, W_lin, b_lin, out);
}